// Round 1
// baseline (560.314 us; speedup 1.0000x reference)
//
#include <hip/hip_runtime.h>
#include <hip/hip_bf16.h>
#include <math.h>

// ---------------------------------------------------------------------------
// GraphSAGE (3-layer, mean aggr) on N=100000 nodes, E=1600000 edges.
// Key identity: mean_agg(x) @ W == mean_agg(x @ W)  (aggregation is linear),
// so we run the node-level GEMMs FIRST, then aggregate narrow messages:
//   layer0: y0 = x  @ [wl0|wr0] (N x 128), h0 = relu(mean_agg(y0[:, :64]) + y0[:,64:] + b0)
//   layer1: y1 = h0 @ [wl1|wr1] (N x 128), h1 = relu(...)
//   layer2: sl = h1 @ wl2, sr = h1 @ wr2 (scalars), out = sigmoid(mean_agg(sl) + sr + b2)
// Aggregation uses a CSR-by-dst built per call (deg count -> scan -> fill),
// shared by all three layers; no float atomics anywhere.
// ---------------------------------------------------------------------------

#define N_NODES_EXPECTED 100000

__global__ __launch_bounds__(256) void zero_i(int* __restrict__ p, int n) {
    int i = blockIdx.x * 256 + threadIdx.x;
    if (i < n) p[i] = 0;
}

__global__ __launch_bounds__(256) void count_deg(const int* __restrict__ dstv,
                                                 int* __restrict__ deg, int E) {
    int e = blockIdx.x * 256 + threadIdx.x;
    if (e < E) atomicAdd(&deg[dstv[e]], 1);
}

// per-256-block exclusive scan; writes partial offsets + block totals
__global__ __launch_bounds__(256) void scan1(const int* __restrict__ deg,
                                             int* __restrict__ offs,
                                             int* __restrict__ bsums, int N) {
    __shared__ int s[256];
    int tid = threadIdx.x;
    int i = blockIdx.x * 256 + tid;
    int v = (i < N) ? deg[i] : 0;
    s[tid] = v;
    __syncthreads();
    for (int d = 1; d < 256; d <<= 1) {
        int t = (tid >= d) ? s[tid - d] : 0;
        __syncthreads();
        s[tid] += t;
        __syncthreads();
    }
    if (i < N) offs[i] = s[tid] - v;  // exclusive within block
    if (tid == 255) bsums[blockIdx.x] = s[255];
}

// single-block exclusive scan of the block sums (nb <= 512)
__global__ __launch_bounds__(512) void scan2(int* __restrict__ bsums, int nb) {
    __shared__ int s[512];
    int tid = threadIdx.x;
    int v = (tid < nb) ? bsums[tid] : 0;
    s[tid] = v;
    __syncthreads();
    for (int d = 1; d < 512; d <<= 1) {
        int t = (tid >= d) ? s[tid - d] : 0;
        __syncthreads();
        s[tid] += t;
        __syncthreads();
    }
    if (tid < nb) bsums[tid] = s[tid] - v;  // exclusive
}

__global__ __launch_bounds__(256) void scan3(int* __restrict__ offs,
                                             const int* __restrict__ bsums,
                                             int* __restrict__ cursor, int N) {
    int i = blockIdx.x * 256 + threadIdx.x;
    if (i < N) {
        int o = offs[i] + bsums[i >> 8];
        offs[i] = o;
        cursor[i] = o;
    }
}

__global__ __launch_bounds__(256) void fill_csr(const int* __restrict__ srcv,
                                                const int* __restrict__ dstv,
                                                int* __restrict__ cursor,
                                                int* __restrict__ csr, int E) {
    int e = blockIdx.x * 256 + threadIdx.x;
    if (e < E) {
        int p = atomicAdd(&cursor[dstv[e]], 1);
        csr[p] = srcv[e];
    }
}

// concat two KxHID weights into Kx128:  out[k][j] = j<64 ? wl[k][j] : wr[k][j-64]
__global__ __launch_bounds__(256) void cat_w(const float* __restrict__ wl,
                                             const float* __restrict__ wr,
                                             float* __restrict__ o, int K) {
    int idx = blockIdx.x * 256 + threadIdx.x;
    if (idx < K * 128) {
        int k = idx >> 7, j = idx & 127;
        o[idx] = (j < 64) ? wl[k * 64 + j] : wr[k * 64 + (j - 64)];
    }
}

// Y[N x 128] = A[N x KTOT] @ W[KTOT x 128]
// block: 64 rows x 128 cols, 256 threads, each thread 4 rows x 8 cols.
template <int KTOT>
__global__ __launch_bounds__(256) void gemm_cat(const float* __restrict__ A,
                                                const float* __restrict__ W,
                                                float* __restrict__ Y, int N) {
    __shared__ float As[64][65];    // +1 pad: row-indexed reads conflict-free
    __shared__ float Ws[64][128];
    const int tid = threadIdx.x;
    const int r0 = blockIdx.x * 64;
    const int tx = tid & 15;   // col group: cols tx*8 .. tx*8+7
    const int ty = tid >> 4;   // row group: rows ty*4 .. ty*4+3

    float acc[4][8];
#pragma unroll
    for (int j = 0; j < 4; ++j)
#pragma unroll
        for (int l = 0; l < 8; ++l) acc[j][l] = 0.f;

    for (int k0 = 0; k0 < KTOT; k0 += 64) {
        // load A tile 64x64 (float4, coalesced)
#pragma unroll
        for (int pass = 0; pass < 4; ++pass) {
            int e = pass * 1024 + tid * 4;
            int row = e >> 6, kk = e & 63;
            float4 v = make_float4(0.f, 0.f, 0.f, 0.f);
            if (r0 + row < N)
                v = *(const float4*)&A[(size_t)(r0 + row) * KTOT + k0 + kk];
            As[row][kk + 0] = v.x;
            As[row][kk + 1] = v.y;
            As[row][kk + 2] = v.z;
            As[row][kk + 3] = v.w;
        }
        // load W tile 64x128 (float4, coalesced)
#pragma unroll
        for (int pass = 0; pass < 8; ++pass) {
            int e = pass * 1024 + tid * 4;
            int kr = e >> 7, cc = e & 127;
            *(float4*)&Ws[kr][cc] = *(const float4*)&W[(size_t)(k0 + kr) * 128 + cc];
        }
        __syncthreads();

#pragma unroll 8
        for (int kk = 0; kk < 64; ++kk) {
            float a0 = As[ty * 4 + 0][kk];
            float a1 = As[ty * 4 + 1][kk];
            float a2 = As[ty * 4 + 2][kk];
            float a3 = As[ty * 4 + 3][kk];
            float4 w0 = *(const float4*)&Ws[kk][tx * 8];
            float4 w1 = *(const float4*)&Ws[kk][tx * 8 + 4];
            float wv[8] = {w0.x, w0.y, w0.z, w0.w, w1.x, w1.y, w1.z, w1.w};
#pragma unroll
            for (int l = 0; l < 8; ++l) {
                acc[0][l] += a0 * wv[l];
                acc[1][l] += a1 * wv[l];
                acc[2][l] += a2 * wv[l];
                acc[3][l] += a3 * wv[l];
            }
        }
        __syncthreads();
    }

#pragma unroll
    for (int j = 0; j < 4; ++j) {
        int r = r0 + ty * 4 + j;
        if (r < N) {
            float4 o0 = make_float4(acc[j][0], acc[j][1], acc[j][2], acc[j][3]);
            float4 o1 = make_float4(acc[j][4], acc[j][5], acc[j][6], acc[j][7]);
            *(float4*)&Y[(size_t)r * 128 + tx * 8] = o0;
            *(float4*)&Y[(size_t)r * 128 + tx * 8 + 4] = o1;
        }
    }
}

// h[i][c] = relu( (sum_{e->i} y[src_e][c]) / max(deg_i,1) + y[i][64+c] + b[c] )
// one wave per node; lane = feature channel (0..63). Each edge gather is one
// coalesced 256B read.
__global__ __launch_bounds__(256) void agg_relu(const float* __restrict__ y,
                                                const int* __restrict__ csr,
                                                const int* __restrict__ offs,
                                                const int* __restrict__ deg,
                                                const float* __restrict__ bias,
                                                float* __restrict__ h, int N) {
    int wid = blockIdx.x * 4 + (threadIdx.x >> 6);
    int lane = threadIdx.x & 63;
    if (wid >= N) return;
    int base = offs[wid];
    int d = deg[wid];
    float acc = 0.f;
    int e = 0;
    for (; e + 4 <= d; e += 4) {
        int s0 = csr[base + e + 0];
        int s1 = csr[base + e + 1];
        int s2 = csr[base + e + 2];
        int s3 = csr[base + e + 3];
        float v0 = y[(size_t)s0 * 128 + lane];
        float v1 = y[(size_t)s1 * 128 + lane];
        float v2 = y[(size_t)s2 * 128 + lane];
        float v3 = y[(size_t)s3 * 128 + lane];
        acc += (v0 + v1) + (v2 + v3);
    }
    for (; e < d; ++e) acc += y[(size_t)csr[base + e] * 128 + lane];
    float m = (d > 0) ? (float)d : 1.f;
    float v = acc / m + y[(size_t)wid * 128 + 64 + lane] + bias[lane];
    h[(size_t)wid * 64 + lane] = fmaxf(v, 0.f);
}

// sl[i] = h1[i] . wl2 ; sr[i] = h1[i] . wr2   (one wave per node, butterfly)
__global__ __launch_bounds__(256) void gemv2(const float* __restrict__ h,
                                             const float* __restrict__ wl,
                                             const float* __restrict__ wr,
                                             float* __restrict__ sl,
                                             float* __restrict__ sr, int N) {
    int wid = blockIdx.x * 4 + (threadIdx.x >> 6);
    int lane = threadIdx.x & 63;
    if (wid >= N) return;
    float hv = h[(size_t)wid * 64 + lane];
    float a = hv * wl[lane];
    float b = hv * wr[lane];
    for (int off = 32; off; off >>= 1) {
        a += __shfl_xor(a, off);
        b += __shfl_xor(b, off);
    }
    if (lane == 0) {
        sl[wid] = a;
        sr[wid] = b;
    }
}

__global__ __launch_bounds__(256) void final_k(const float* __restrict__ sl,
                                               const float* __restrict__ sr,
                                               const int* __restrict__ csr,
                                               const int* __restrict__ offs,
                                               const int* __restrict__ deg,
                                               const float* __restrict__ b2,
                                               float* __restrict__ out, int N) {
    int i = blockIdx.x * 256 + threadIdx.x;
    if (i >= N) return;
    int base = offs[i];
    int d = deg[i];
    float acc = 0.f;
    for (int e = 0; e < d; ++e) acc += sl[csr[base + e]];
    float m = (d > 0) ? (float)d : 1.f;
    float v = acc / m + sr[i] + b2[0];
    out[i] = 1.f / (1.f + expf(-v));
}

extern "C" void kernel_launch(void* const* d_in, const int* in_sizes, int n_in,
                              void* d_out, int out_size, void* d_ws, size_t ws_size,
                              hipStream_t stream) {
    const float* x  = (const float*)d_in[0];
    const int*  ei  = (const int*)d_in[1];
    const float* wl0 = (const float*)d_in[2];
    const float* wr0 = (const float*)d_in[3];
    const float* b0  = (const float*)d_in[4];
    const float* wl1 = (const float*)d_in[5];
    const float* wr1 = (const float*)d_in[6];
    const float* b1  = (const float*)d_in[7];
    const float* wl2 = (const float*)d_in[8];
    const float* wr2 = (const float*)d_in[9];
    const float* b2  = (const float*)d_in[10];
    float* out = (float*)d_out;

    const int E = in_sizes[1] / 2;
    const int N = out_size;              // 100000, OUT_DIM = 1
    const int* srcv = ei;
    const int* dstv = ei + E;

    // workspace carve-up (256B aligned slabs)
    char* ws = (char*)d_ws;
    size_t o = 0;
    auto take = [&](size_t nbytes) -> void* {
        void* p = ws + o;
        o = (o + nbytes + 255) & ~(size_t)255;
        return p;
    };
    int* deg    = (int*)take((size_t)N * 4);
    int* cursor = (int*)take((size_t)N * 4);
    int* offs   = (int*)take((size_t)N * 4);
    int* bsums  = (int*)take(1024 * 4);
    int* csr    = (int*)take((size_t)E * 4);
    float* w0c  = (float*)take(128 * 128 * 4);
    float* w1c  = (float*)take(64 * 128 * 4);
    float* y    = (float*)take((size_t)N * 128 * 4);
    float* h    = (float*)take((size_t)N * 64 * 4);
    float* sl   = y;          // reuse y for layer-2 scalars
    float* sr   = y + N;
    (void)ws_size;

    const int nbN = (N + 255) / 256;       // 391
    const int nbE = (E + 255) / 256;
    const int nbW = (N + 3) / 4;           // wave-per-node grids
    const int nbG = (N + 63) / 64;         // gemm grid

    // CSR build (shared by all 3 layers)
    zero_i<<<nbN, 256, 0, stream>>>(deg, N);
    count_deg<<<nbE, 256, 0, stream>>>(dstv, deg, E);
    scan1<<<nbN, 256, 0, stream>>>(deg, offs, bsums, N);
    scan2<<<1, 512, 0, stream>>>(bsums, nbN);
    scan3<<<nbN, 256, 0, stream>>>(offs, bsums, cursor, N);
    fill_csr<<<nbE, 256, 0, stream>>>(srcv, dstv, cursor, csr, E);

    // weight concat
    cat_w<<<(128 * 128 + 255) / 256, 256, 0, stream>>>(wl0, wr0, w0c, 128);
    cat_w<<<(64 * 128 + 255) / 256, 256, 0, stream>>>(wl1, wr1, w1c, 64);

    // layer 0
    gemm_cat<128><<<nbG, 256, 0, stream>>>(x, w0c, y, N);
    agg_relu<<<nbW, 256, 0, stream>>>(y, csr, offs, deg, b0, h, N);
    // layer 1
    gemm_cat<64><<<nbG, 256, 0, stream>>>(h, w1c, y, N);
    agg_relu<<<nbW, 256, 0, stream>>>(y, csr, offs, deg, b1, h, N);
    // layer 2 + sigmoid
    gemv2<<<nbW, 256, 0, stream>>>(h, wl2, wr2, sl, sr, N);
    final_k<<<nbN, 256, 0, stream>>>(sl, sr, csr, offs, deg, b2, out, N);
}

// Round 2
// 414.501 us; speedup vs baseline: 1.3518x; 1.3518x over previous
//
#include <hip/hip_runtime.h>
#include <hip/hip_bf16.h>
#include <math.h>

// ---------------------------------------------------------------------------
// GraphSAGE (3-layer, mean aggr) on N=100000 nodes, E=1600000 edges.
// mean_agg(x) @ W == mean_agg(x @ W): GEMMs first, aggregate narrow messages.
// CSR-by-dst built per call via a TWO-LEVEL COUNTING SORT (round 1's direct
// atomic scatter showed 105 MB WRITE_SIZE / 134 us on fill_csr — 16x line
// amplification from random 4B stores):
//   A) bucket edges by dst>>7 (782 buckets) with LDS-staged, run-contiguous
//      scatter (packed 4B: src<<7 | dst&127)
//   B) one block per bucket: per-dst LDS hist/scan/cursor -> deg, offs, csr;
//      all scattered csr writes land in that bucket's ~8KB window (L2-local).
// No float atomics anywhere.
// ---------------------------------------------------------------------------

#define SHIFT 7
#define BKT 128           // dsts per bucket
#define CHUNK 4096        // edges per scatter block

__global__ __launch_bounds__(256) void zero_i(int* __restrict__ p, int n) {
    int i = blockIdx.x * 256 + threadIdx.x;
    if (i < n) p[i] = 0;
}

// ---- pass A1: histogram of dst>>SHIFT, LDS-privatized ----
__global__ __launch_bounds__(256) void hist_bucket(const int* __restrict__ dstv,
                                                   int* __restrict__ bucket_cnt,
                                                   int E, int NB) {
    __shared__ int h[1024];
    for (int i = threadIdx.x; i < NB; i += 256) h[i] = 0;
    __syncthreads();
    int base = blockIdx.x * CHUNK;
#pragma unroll
    for (int k = 0; k < CHUNK / 256; ++k) {
        int e = base + threadIdx.x + k * 256;
        if (e < E) atomicAdd(&h[dstv[e] >> SHIFT], 1);
    }
    __syncthreads();
    for (int i = threadIdx.x; i < NB; i += 256)
        if (h[i]) atomicAdd(&bucket_cnt[i], h[i]);
}

// ---- pass A2: exclusive scan of bucket counts (NB <= 1024), 1 block ----
__global__ __launch_bounds__(1024) void scan_bucket(const int* __restrict__ cnt,
                                                    int* __restrict__ boff,
                                                    int* __restrict__ bcur, int NB) {
    __shared__ int s[1024];
    int t = threadIdx.x;
    int v = (t < NB) ? cnt[t] : 0;
    s[t] = v;
    __syncthreads();
    for (int d = 1; d < 1024; d <<= 1) {
        int x = (t >= d) ? s[t - d] : 0;
        __syncthreads();
        s[t] += x;
        __syncthreads();
    }
    if (t < NB) {
        int o = s[t] - v;
        boff[t] = o;
        bcur[t] = o;
    }
    if (t == NB - 1) boff[NB] = s[t];
}

// ---- pass A3: scatter edges into bucket-contiguous storage, LDS-staged ----
__global__ __launch_bounds__(256) void scatter_bucket(const int* __restrict__ srcv,
                                                      const int* __restrict__ dstv,
                                                      int* __restrict__ bcur,
                                                      int* __restrict__ bucketed,
                                                      int E, int NB) {
    __shared__ int hist[1024];
    __shared__ int offl[1024];
    __shared__ int basel[1024];
    __shared__ int partial[256];
    __shared__ int posA[CHUNK];
    __shared__ int valA[CHUNK];
    const int t = threadIdx.x;
    for (int i = t; i < NB; i += 256) hist[i] = 0;
    __syncthreads();

    const int cbase = blockIdx.x * CHUNK;
    int bk[CHUNK / 256], rk[CHUNK / 256], vv[CHUNK / 256];
#pragma unroll
    for (int k = 0; k < CHUNK / 256; ++k) {
        int e = cbase + t + k * 256;
        if (e < E) {
            int d = dstv[e];
            int s = srcv[e];
            int b = d >> SHIFT;
            bk[k] = b;
            rk[k] = atomicAdd(&hist[b], 1);
            vv[k] = (s << SHIFT) | (d & (BKT - 1));
        } else {
            bk[k] = -1;
        }
    }
    __syncthreads();

    // reserve contiguous global runs (one atomic per non-empty bucket)
    for (int b = t; b < NB; b += 256) {
        int c = hist[b];
        basel[b] = c ? atomicAdd(&bcur[b], c) : 0;
    }
    // exclusive block scan of hist -> offl (4 elems/thread, contiguous groups)
    {
        int g = t * 4;
        int a0 = (g + 0 < NB) ? hist[g + 0] : 0;
        int a1 = (g + 1 < NB) ? hist[g + 1] : 0;
        int a2 = (g + 2 < NB) ? hist[g + 2] : 0;
        int a3 = (g + 3 < NB) ? hist[g + 3] : 0;
        int sum = a0 + a1 + a2 + a3;
        partial[t] = sum;
        __syncthreads();
        for (int d = 1; d < 256; d <<= 1) {
            int x = (t >= d) ? partial[t - d] : 0;
            __syncthreads();
            partial[t] += x;
            __syncthreads();
        }
        int ex = partial[t] - sum;
        if (g + 0 < NB) offl[g + 0] = ex;
        if (g + 1 < NB) offl[g + 1] = ex + a0;
        if (g + 2 < NB) offl[g + 2] = ex + a0 + a1;
        if (g + 3 < NB) offl[g + 3] = ex + a0 + a1 + a2;
    }
    __syncthreads();

    int nloc = E - cbase;
    if (nloc > CHUNK) nloc = CHUNK;
#pragma unroll
    for (int k = 0; k < CHUNK / 256; ++k) {
        if (bk[k] >= 0) {
            int slot = offl[bk[k]] + rk[k];
            posA[slot] = basel[bk[k]] + rk[k];
            valA[slot] = vv[k];
        }
    }
    __syncthreads();
    // bucket-sorted write-out: consecutive threads hit consecutive addresses
    for (int j = t; j < nloc; j += 256) bucketed[posA[j]] = valA[j];
}

// ---- pass B: per-bucket counting sort by exact dst -> deg, offs, csr ----
__global__ __launch_bounds__(256) void sort_bucket(const int* __restrict__ bucketed,
                                                   const int* __restrict__ boff,
                                                   int* __restrict__ deg,
                                                   int* __restrict__ offs,
                                                   int* __restrict__ csr, int N) {
    __shared__ int cnt[BKT];
    __shared__ int sc[BKT];
    __shared__ int cur[BKT];
    const int b = blockIdx.x;
    const int t = threadIdx.x;
    const int ebase = boff[b], eend = boff[b + 1];
    if (t < BKT) cnt[t] = 0;
    __syncthreads();
    for (int i = ebase + t; i < eend; i += 256)
        atomicAdd(&cnt[bucketed[i] & (BKT - 1)], 1);
    __syncthreads();
    int v = (t < BKT) ? cnt[t] : 0;
    if (t < BKT) sc[t] = v;
    __syncthreads();
    for (int d = 1; d < BKT; d <<= 1) {
        int x = (t < BKT && t >= d) ? sc[t - d] : 0;
        __syncthreads();
        if (t < BKT) sc[t] += x;
        __syncthreads();
    }
    if (t < BKT) {
        int ex = sc[t] - v;
        cur[t] = ex;
        int dst = (b << SHIFT) + t;
        if (dst < N) {
            deg[dst] = v;
            offs[dst] = ebase + ex;
        }
    }
    __syncthreads();
    for (int i = ebase + t; i < eend; i += 256) {
        int w = bucketed[i];
        int p = atomicAdd(&cur[w & (BKT - 1)], 1);
        csr[ebase + p] = w >> SHIFT;   // scattered, but within ~8KB window
    }
}

// concat two KxHID weights into Kx128
__global__ __launch_bounds__(256) void cat_w(const float* __restrict__ wl,
                                             const float* __restrict__ wr,
                                             float* __restrict__ o, int K) {
    int idx = blockIdx.x * 256 + threadIdx.x;
    if (idx < K * 128) {
        int k = idx >> 7, j = idx & 127;
        o[idx] = (j < 64) ? wl[k * 64 + j] : wr[k * 64 + (j - 64)];
    }
}

// Y[N x 128] = A[N x KTOT] @ W[KTOT x 128]
template <int KTOT>
__global__ __launch_bounds__(256) void gemm_cat(const float* __restrict__ A,
                                                const float* __restrict__ W,
                                                float* __restrict__ Y, int N) {
    __shared__ float As[64][65];
    __shared__ float Ws[64][128];
    const int tid = threadIdx.x;
    const int r0 = blockIdx.x * 64;
    const int tx = tid & 15;
    const int ty = tid >> 4;

    float acc[4][8];
#pragma unroll
    for (int j = 0; j < 4; ++j)
#pragma unroll
        for (int l = 0; l < 8; ++l) acc[j][l] = 0.f;

    for (int k0 = 0; k0 < KTOT; k0 += 64) {
#pragma unroll
        for (int pass = 0; pass < 4; ++pass) {
            int e = pass * 1024 + tid * 4;
            int row = e >> 6, kk = e & 63;
            float4 v = make_float4(0.f, 0.f, 0.f, 0.f);
            if (r0 + row < N)
                v = *(const float4*)&A[(size_t)(r0 + row) * KTOT + k0 + kk];
            As[row][kk + 0] = v.x;
            As[row][kk + 1] = v.y;
            As[row][kk + 2] = v.z;
            As[row][kk + 3] = v.w;
        }
#pragma unroll
        for (int pass = 0; pass < 8; ++pass) {
            int e = pass * 1024 + tid * 4;
            int kr = e >> 7, cc = e & 127;
            *(float4*)&Ws[kr][cc] = *(const float4*)&W[(size_t)(k0 + kr) * 128 + cc];
        }
        __syncthreads();

#pragma unroll 8
        for (int kk = 0; kk < 64; ++kk) {
            float a0 = As[ty * 4 + 0][kk];
            float a1 = As[ty * 4 + 1][kk];
            float a2 = As[ty * 4 + 2][kk];
            float a3 = As[ty * 4 + 3][kk];
            float4 w0 = *(const float4*)&Ws[kk][tx * 8];
            float4 w1 = *(const float4*)&Ws[kk][tx * 8 + 4];
            float wv[8] = {w0.x, w0.y, w0.z, w0.w, w1.x, w1.y, w1.z, w1.w};
#pragma unroll
            for (int l = 0; l < 8; ++l) {
                acc[0][l] += a0 * wv[l];
                acc[1][l] += a1 * wv[l];
                acc[2][l] += a2 * wv[l];
                acc[3][l] += a3 * wv[l];
            }
        }
        __syncthreads();
    }

#pragma unroll
    for (int j = 0; j < 4; ++j) {
        int r = r0 + ty * 4 + j;
        if (r < N) {
            float4 o0 = make_float4(acc[j][0], acc[j][1], acc[j][2], acc[j][3]);
            float4 o1 = make_float4(acc[j][4], acc[j][5], acc[j][6], acc[j][7]);
            *(float4*)&Y[(size_t)r * 128 + tx * 8] = o0;
            *(float4*)&Y[(size_t)r * 128 + tx * 8 + 4] = o1;
        }
    }
}

// h[i][c] = relu( mean_{e->i} y[src_e][c] + y[i][64+c] + b[c] )
__global__ __launch_bounds__(256) void agg_relu(const float* __restrict__ y,
                                                const int* __restrict__ csr,
                                                const int* __restrict__ offs,
                                                const int* __restrict__ deg,
                                                const float* __restrict__ bias,
                                                float* __restrict__ h, int N) {
    int wid = blockIdx.x * 4 + (threadIdx.x >> 6);
    int lane = threadIdx.x & 63;
    if (wid >= N) return;
    int base = offs[wid];
    int d = deg[wid];
    float acc = 0.f;
    int e = 0;
    for (; e + 4 <= d; e += 4) {
        int s0 = csr[base + e + 0];
        int s1 = csr[base + e + 1];
        int s2 = csr[base + e + 2];
        int s3 = csr[base + e + 3];
        float v0 = y[(size_t)s0 * 128 + lane];
        float v1 = y[(size_t)s1 * 128 + lane];
        float v2 = y[(size_t)s2 * 128 + lane];
        float v3 = y[(size_t)s3 * 128 + lane];
        acc += (v0 + v1) + (v2 + v3);
    }
    for (; e < d; ++e) acc += y[(size_t)csr[base + e] * 128 + lane];
    float m = (d > 0) ? (float)d : 1.f;
    float v = acc / m + y[(size_t)wid * 128 + 64 + lane] + bias[lane];
    h[(size_t)wid * 64 + lane] = fmaxf(v, 0.f);
}

__global__ __launch_bounds__(256) void gemv2(const float* __restrict__ h,
                                             const float* __restrict__ wl,
                                             const float* __restrict__ wr,
                                             float* __restrict__ sl,
                                             float* __restrict__ sr, int N) {
    int wid = blockIdx.x * 4 + (threadIdx.x >> 6);
    int lane = threadIdx.x & 63;
    if (wid >= N) return;
    float hv = h[(size_t)wid * 64 + lane];
    float a = hv * wl[lane];
    float b = hv * wr[lane];
    for (int off = 32; off; off >>= 1) {
        a += __shfl_xor(a, off);
        b += __shfl_xor(b, off);
    }
    if (lane == 0) {
        sl[wid] = a;
        sr[wid] = b;
    }
}

__global__ __launch_bounds__(256) void final_k(const float* __restrict__ sl,
                                               const float* __restrict__ sr,
                                               const int* __restrict__ csr,
                                               const int* __restrict__ offs,
                                               const int* __restrict__ deg,
                                               const float* __restrict__ b2,
                                               float* __restrict__ out, int N) {
    int i = blockIdx.x * 256 + threadIdx.x;
    if (i >= N) return;
    int base = offs[i];
    int d = deg[i];
    float acc = 0.f;
    for (int e = 0; e < d; ++e) acc += sl[csr[base + e]];
    float m = (d > 0) ? (float)d : 1.f;
    float v = acc / m + sr[i] + b2[0];
    out[i] = 1.f / (1.f + expf(-v));
}

extern "C" void kernel_launch(void* const* d_in, const int* in_sizes, int n_in,
                              void* d_out, int out_size, void* d_ws, size_t ws_size,
                              hipStream_t stream) {
    const float* x  = (const float*)d_in[0];
    const int*  ei  = (const int*)d_in[1];
    const float* wl0 = (const float*)d_in[2];
    const float* wr0 = (const float*)d_in[3];
    const float* b0  = (const float*)d_in[4];
    const float* wl1 = (const float*)d_in[5];
    const float* wr1 = (const float*)d_in[6];
    const float* b1  = (const float*)d_in[7];
    const float* wl2 = (const float*)d_in[8];
    const float* wr2 = (const float*)d_in[9];
    const float* b2  = (const float*)d_in[10];
    float* out = (float*)d_out;

    const int E = in_sizes[1] / 2;
    const int N = out_size;
    const int* srcv = ei;
    const int* dstv = ei + E;
    const int NB = (N + BKT - 1) >> SHIFT;   // 782 for N=100000

    char* ws = (char*)d_ws;
    size_t o = 0;
    auto take = [&](size_t nbytes) -> void* {
        void* p = ws + o;
        o = (o + nbytes + 255) & ~(size_t)255;
        return p;
    };
    int* deg    = (int*)take((size_t)N * 4);
    int* offs   = (int*)take((size_t)N * 4);
    int* bcnt   = (int*)take((size_t)(NB + 2) * 4);
    int* boff   = (int*)take((size_t)(NB + 2) * 4);
    int* bcur   = (int*)take((size_t)(NB + 2) * 4);
    int* csr    = (int*)take((size_t)E * 4);
    float* w0c  = (float*)take(128 * 128 * 4);
    float* w1c  = (float*)take(64 * 128 * 4);
    float* y    = (float*)take((size_t)N * 128 * 4);
    float* h    = (float*)take((size_t)N * 64 * 4);
    int* bucketed = (int*)y;      // consumed by sort_bucket before gemm writes y
    float* sl   = y;              // layer-2 scalars, reuse y again
    float* sr   = y + N;
    (void)ws_size;

    const int nbN = (N + 255) / 256;
    const int nbC = (E + CHUNK - 1) / CHUNK;   // 391
    const int nbW = (N + 3) / 4;
    const int nbG = (N + 63) / 64;

    // CSR build: two-level counting sort (shared by all 3 layers)
    zero_i<<<(NB + 255) / 256, 256, 0, stream>>>(bcnt, NB);
    hist_bucket<<<nbC, 256, 0, stream>>>(dstv, bcnt, E, NB);
    scan_bucket<<<1, 1024, 0, stream>>>(bcnt, boff, bcur, NB);
    scatter_bucket<<<nbC, 256, 0, stream>>>(srcv, dstv, bcur, bucketed, E, NB);
    sort_bucket<<<NB, 256, 0, stream>>>(bucketed, boff, deg, offs, csr, N);

    cat_w<<<(128 * 128 + 255) / 256, 256, 0, stream>>>(wl0, wr0, w0c, 128);
    cat_w<<<(64 * 128 + 255) / 256, 256, 0, stream>>>(wl1, wr1, w1c, 64);

    // layer 0
    gemm_cat<128><<<nbG, 256, 0, stream>>>(x, w0c, y, N);
    agg_relu<<<nbW, 256, 0, stream>>>(y, csr, offs, deg, b0, h, N);
    // layer 1
    gemm_cat<64><<<nbG, 256, 0, stream>>>(h, w1c, y, N);
    agg_relu<<<nbW, 256, 0, stream>>>(y, csr, offs, deg, b1, h, N);
    // layer 2 + sigmoid
    gemv2<<<nbW, 256, 0, stream>>>(h, wl2, wr2, sl, sr, N);
    final_k<<<nbN, 256, 0, stream>>>(sl, sr, csr, offs, deg, b2, out, N);
}

// Round 3
// 366.708 us; speedup vs baseline: 1.5280x; 1.1303x over previous
//
#include <hip/hip_runtime.h>
#include <hip/hip_bf16.h>
#include <math.h>

// ---------------------------------------------------------------------------
// GraphSAGE (3-layer, mean aggr), N=100000, E=1600000.
// mean_agg(x) @ W == mean_agg(x @ W): GEMMs first, aggregate narrow messages.
// R2->R3: GEMMs moved to bf16 MFMA (no LDS, swapped operands so each lane
// stores 4 packed bf16 cols); all messages (y, h) stored bf16 so the edge
// gather in agg_relu reads 128 B/edge instead of 256 B.
// CSR built per call via two-level counting sort (R2, unchanged).
// ---------------------------------------------------------------------------

#define SHIFT 7
#define BKT 128
#define CHUNK 4096

typedef __bf16 bf16_t;
typedef bf16_t bf16x8 __attribute__((ext_vector_type(8)));
typedef float f32x4 __attribute__((ext_vector_type(4)));

__global__ __launch_bounds__(256) void zero_i(int* __restrict__ p, int n) {
    int i = blockIdx.x * 256 + threadIdx.x;
    if (i < n) p[i] = 0;
}

// ---- CSR build pass A1: histogram of dst>>SHIFT ----
__global__ __launch_bounds__(256) void hist_bucket(const int* __restrict__ dstv,
                                                   int* __restrict__ bucket_cnt,
                                                   int E, int NB) {
    __shared__ int h[1024];
    for (int i = threadIdx.x; i < NB; i += 256) h[i] = 0;
    __syncthreads();
    int base = blockIdx.x * CHUNK;
#pragma unroll
    for (int k = 0; k < CHUNK / 256; ++k) {
        int e = base + threadIdx.x + k * 256;
        if (e < E) atomicAdd(&h[dstv[e] >> SHIFT], 1);
    }
    __syncthreads();
    for (int i = threadIdx.x; i < NB; i += 256)
        if (h[i]) atomicAdd(&bucket_cnt[i], h[i]);
}

// ---- pass A2: exclusive scan of bucket counts ----
__global__ __launch_bounds__(1024) void scan_bucket(const int* __restrict__ cnt,
                                                    int* __restrict__ boff,
                                                    int* __restrict__ bcur, int NB) {
    __shared__ int s[1024];
    int t = threadIdx.x;
    int v = (t < NB) ? cnt[t] : 0;
    s[t] = v;
    __syncthreads();
    for (int d = 1; d < 1024; d <<= 1) {
        int x = (t >= d) ? s[t - d] : 0;
        __syncthreads();
        s[t] += x;
        __syncthreads();
    }
    if (t < NB) {
        int o = s[t] - v;
        boff[t] = o;
        bcur[t] = o;
    }
    if (t == NB - 1) boff[NB] = s[t];
}

// ---- pass A3: LDS-staged bucket scatter ----
__global__ __launch_bounds__(256) void scatter_bucket(const int* __restrict__ srcv,
                                                      const int* __restrict__ dstv,
                                                      int* __restrict__ bcur,
                                                      int* __restrict__ bucketed,
                                                      int E, int NB) {
    __shared__ int hist[1024];
    __shared__ int offl[1024];
    __shared__ int basel[1024];
    __shared__ int partial[256];
    __shared__ int posA[CHUNK];
    __shared__ int valA[CHUNK];
    const int t = threadIdx.x;
    for (int i = t; i < NB; i += 256) hist[i] = 0;
    __syncthreads();

    const int cbase = blockIdx.x * CHUNK;
    int bk[CHUNK / 256], rk[CHUNK / 256], vv[CHUNK / 256];
#pragma unroll
    for (int k = 0; k < CHUNK / 256; ++k) {
        int e = cbase + t + k * 256;
        if (e < E) {
            int d = dstv[e];
            int s = srcv[e];
            int b = d >> SHIFT;
            bk[k] = b;
            rk[k] = atomicAdd(&hist[b], 1);
            vv[k] = (s << SHIFT) | (d & (BKT - 1));
        } else {
            bk[k] = -1;
        }
    }
    __syncthreads();

    for (int b = t; b < NB; b += 256) {
        int c = hist[b];
        basel[b] = c ? atomicAdd(&bcur[b], c) : 0;
    }
    {
        int g = t * 4;
        int a0 = (g + 0 < NB) ? hist[g + 0] : 0;
        int a1 = (g + 1 < NB) ? hist[g + 1] : 0;
        int a2 = (g + 2 < NB) ? hist[g + 2] : 0;
        int a3 = (g + 3 < NB) ? hist[g + 3] : 0;
        int sum = a0 + a1 + a2 + a3;
        partial[t] = sum;
        __syncthreads();
        for (int d = 1; d < 256; d <<= 1) {
            int x = (t >= d) ? partial[t - d] : 0;
            __syncthreads();
            partial[t] += x;
            __syncthreads();
        }
        int ex = partial[t] - sum;
        if (g + 0 < NB) offl[g + 0] = ex;
        if (g + 1 < NB) offl[g + 1] = ex + a0;
        if (g + 2 < NB) offl[g + 2] = ex + a0 + a1;
        if (g + 3 < NB) offl[g + 3] = ex + a0 + a1 + a2;
    }
    __syncthreads();

    int nloc = E - cbase;
    if (nloc > CHUNK) nloc = CHUNK;
#pragma unroll
    for (int k = 0; k < CHUNK / 256; ++k) {
        if (bk[k] >= 0) {
            int slot = offl[bk[k]] + rk[k];
            posA[slot] = basel[bk[k]] + rk[k];
            valA[slot] = vv[k];
        }
    }
    __syncthreads();
    for (int j = t; j < nloc; j += 256) bucketed[posA[j]] = valA[j];
}

// ---- pass B: per-bucket counting sort -> deg, offs, csr ----
__global__ __launch_bounds__(256) void sort_bucket(const int* __restrict__ bucketed,
                                                   const int* __restrict__ boff,
                                                   int* __restrict__ deg,
                                                   int* __restrict__ offs,
                                                   int* __restrict__ csr, int N) {
    __shared__ int cnt[BKT];
    __shared__ int sc[BKT];
    __shared__ int cur[BKT];
    const int b = blockIdx.x;
    const int t = threadIdx.x;
    const int ebase = boff[b], eend = boff[b + 1];
    if (t < BKT) cnt[t] = 0;
    __syncthreads();
    for (int i = ebase + t; i < eend; i += 256)
        atomicAdd(&cnt[bucketed[i] & (BKT - 1)], 1);
    __syncthreads();
    int v = (t < BKT) ? cnt[t] : 0;
    if (t < BKT) sc[t] = v;
    __syncthreads();
    for (int d = 1; d < BKT; d <<= 1) {
        int x = (t < BKT && t >= d) ? sc[t - d] : 0;
        __syncthreads();
        if (t < BKT) sc[t] += x;
        __syncthreads();
    }
    if (t < BKT) {
        int ex = sc[t] - v;
        cur[t] = ex;
        int dst = (b << SHIFT) + t;
        if (dst < N) {
            deg[dst] = v;
            offs[dst] = ebase + ex;
        }
    }
    __syncthreads();
    for (int i = ebase + t; i < eend; i += 256) {
        int w = bucketed[i];
        int p = atomicAdd(&cur[w & (BKT - 1)], 1);
        csr[ebase + p] = w >> SHIFT;
    }
}

// wt[j][k] = bf16( j<64 ? wl[k][j] : wr[k][j-64] ), j in [0,128), k in [0,K)
__global__ __launch_bounds__(256) void cat_wt(const float* __restrict__ wl,
                                              const float* __restrict__ wr,
                                              bf16_t* __restrict__ wt,
                                              int K, int klog2) {
    int idx = blockIdx.x * 256 + threadIdx.x;
    if (idx < K * 128) {
        int j = idx >> klog2;
        int k = idx & (K - 1);
        float v = (j < 64) ? wl[k * 64 + j] : wr[k * 64 + (j - 64)];
        wt[idx] = (bf16_t)v;
    }
}

// Y[N x 128] (bf16) = A[N x KTOT] @ W[KTOT x 128], via 16x16x32 bf16 MFMA.
// Swapped operands: A-operand = Wt (m = out-col), B-operand = node rows
// (n = node-row). D: m = quad*4+reg (out-col), n = lane&15 (node-row) ->
// each lane stores 4 consecutive out-cols as one packed 8 B write.
template <int KTOT, bool AIN_BF16>
__global__ __launch_bounds__(256) void gemm_mfma(const void* __restrict__ Ain,
                                                 const bf16_t* __restrict__ Wt,
                                                 bf16_t* __restrict__ Y, int N) {
    const int lane = threadIdx.x & 63;
    const int wv = threadIdx.x >> 6;
    const int r0 = blockIdx.x * 64 + wv * 16;
    const int rr = lane & 15;
    const int quad = lane >> 4;
    const int row_store = r0 + rr;
    int row = (row_store < N) ? row_store : (N - 1);
    constexpr int NK = KTOT / 32;

    bf16x8 xf[NK];
    if (AIN_BF16) {
        const bf16_t* A = (const bf16_t*)Ain;
#pragma unroll
        for (int kk = 0; kk < NK; ++kk)
            xf[kk] = *(const bf16x8*)&A[(size_t)row * KTOT + kk * 32 + quad * 8];
    } else {
        const float* A = (const float*)Ain;
#pragma unroll
        for (int kk = 0; kk < NK; ++kk) {
            const float* ap = &A[(size_t)row * KTOT + kk * 32 + quad * 8];
            float4 f0 = *(const float4*)ap;
            float4 f1 = *(const float4*)(ap + 4);
            union { bf16x8 v; bf16_t h[8]; } u;
            u.h[0] = (bf16_t)f0.x; u.h[1] = (bf16_t)f0.y;
            u.h[2] = (bf16_t)f0.z; u.h[3] = (bf16_t)f0.w;
            u.h[4] = (bf16_t)f1.x; u.h[5] = (bf16_t)f1.y;
            u.h[6] = (bf16_t)f1.z; u.h[7] = (bf16_t)f1.w;
            xf[kk] = u.v;
        }
    }

#pragma unroll
    for (int c = 0; c < 8; ++c) {
        f32x4 acc = {0.f, 0.f, 0.f, 0.f};
#pragma unroll
        for (int kk = 0; kk < NK; ++kk) {
            bf16x8 wf = *(const bf16x8*)&Wt[(size_t)(c * 16 + rr) * KTOT + kk * 32 + quad * 8];
            acc = __builtin_amdgcn_mfma_f32_16x16x32_bf16(wf, xf[kk], acc, 0, 0, 0);
        }
        if (row_store < N) {
            union { bf16_t h[4]; uint2 u; } p;
            p.h[0] = (bf16_t)acc[0]; p.h[1] = (bf16_t)acc[1];
            p.h[2] = (bf16_t)acc[2]; p.h[3] = (bf16_t)acc[3];
            *(uint2*)&Y[(size_t)row_store * 128 + c * 16 + quad * 4] = p.u;
        }
    }
}

// h[i][c] = relu( mean_{e->i} y[src_e][c] + y[i][64+c] + b[c] ), all bf16 msgs
__global__ __launch_bounds__(256) void agg_relu(const bf16_t* __restrict__ y,
                                                const int* __restrict__ csr,
                                                const int* __restrict__ offs,
                                                const int* __restrict__ deg,
                                                const float* __restrict__ bias,
                                                bf16_t* __restrict__ h, int N) {
    int wid = blockIdx.x * 4 + (threadIdx.x >> 6);
    int lane = threadIdx.x & 63;
    if (wid >= N) return;
    int base = offs[wid];
    int d = deg[wid];
    float acc = 0.f;
    int e = 0;
    for (; e + 4 <= d; e += 4) {
        int s0 = csr[base + e + 0];
        int s1 = csr[base + e + 1];
        int s2 = csr[base + e + 2];
        int s3 = csr[base + e + 3];
        float v0 = (float)y[(size_t)s0 * 128 + lane];
        float v1 = (float)y[(size_t)s1 * 128 + lane];
        float v2 = (float)y[(size_t)s2 * 128 + lane];
        float v3 = (float)y[(size_t)s3 * 128 + lane];
        acc += (v0 + v1) + (v2 + v3);
    }
    for (; e < d; ++e) acc += (float)y[(size_t)csr[base + e] * 128 + lane];
    float m = (d > 0) ? (float)d : 1.f;
    float v = acc / m + (float)y[(size_t)wid * 128 + 64 + lane] + bias[lane];
    h[(size_t)wid * 64 + lane] = (bf16_t)fmaxf(v, 0.f);
}

__global__ __launch_bounds__(256) void gemv2(const bf16_t* __restrict__ h,
                                             const float* __restrict__ wl,
                                             const float* __restrict__ wr,
                                             float* __restrict__ sl,
                                             float* __restrict__ sr, int N) {
    int wid = blockIdx.x * 4 + (threadIdx.x >> 6);
    int lane = threadIdx.x & 63;
    if (wid >= N) return;
    float hv = (float)h[(size_t)wid * 64 + lane];
    float a = hv * wl[lane];
    float b = hv * wr[lane];
    for (int off = 32; off; off >>= 1) {
        a += __shfl_xor(a, off);
        b += __shfl_xor(b, off);
    }
    if (lane == 0) {
        sl[wid] = a;
        sr[wid] = b;
    }
}

__global__ __launch_bounds__(256) void final_k(const float* __restrict__ sl,
                                               const float* __restrict__ sr,
                                               const int* __restrict__ csr,
                                               const int* __restrict__ offs,
                                               const int* __restrict__ deg,
                                               const float* __restrict__ b2,
                                               float* __restrict__ out, int N) {
    int i = blockIdx.x * 256 + threadIdx.x;
    if (i >= N) return;
    int base = offs[i];
    int d = deg[i];
    float acc = 0.f;
    for (int e = 0; e < d; ++e) acc += sl[csr[base + e]];
    float m = (d > 0) ? (float)d : 1.f;
    float v = acc / m + sr[i] + b2[0];
    out[i] = 1.f / (1.f + expf(-v));
}

extern "C" void kernel_launch(void* const* d_in, const int* in_sizes, int n_in,
                              void* d_out, int out_size, void* d_ws, size_t ws_size,
                              hipStream_t stream) {
    const float* x  = (const float*)d_in[0];
    const int*  ei  = (const int*)d_in[1];
    const float* wl0 = (const float*)d_in[2];
    const float* wr0 = (const float*)d_in[3];
    const float* b0  = (const float*)d_in[4];
    const float* wl1 = (const float*)d_in[5];
    const float* wr1 = (const float*)d_in[6];
    const float* b1  = (const float*)d_in[7];
    const float* wl2 = (const float*)d_in[8];
    const float* wr2 = (const float*)d_in[9];
    const float* b2  = (const float*)d_in[10];
    float* out = (float*)d_out;

    const int E = in_sizes[1] / 2;
    const int N = out_size;
    const int* srcv = ei;
    const int* dstv = ei + E;
    const int NB = (N + BKT - 1) >> SHIFT;   // 782

    char* ws = (char*)d_ws;
    size_t o = 0;
    auto take = [&](size_t nbytes) -> void* {
        void* p = ws + o;
        o = (o + nbytes + 255) & ~(size_t)255;
        return p;
    };
    int* deg    = (int*)take((size_t)N * 4);
    int* offs   = (int*)take((size_t)N * 4);
    int* bcnt   = (int*)take((size_t)(NB + 2) * 4);
    int* boff   = (int*)take((size_t)(NB + 2) * 4);
    int* bcur   = (int*)take((size_t)(NB + 2) * 4);
    int* csr    = (int*)take((size_t)E * 4);
    bf16_t* w0t = (bf16_t*)take(128 * 128 * 2);
    bf16_t* w1t = (bf16_t*)take(128 * 64 * 2);
    bf16_t* y   = (bf16_t*)take((size_t)N * 128 * 2);
    bf16_t* h   = (bf16_t*)take((size_t)N * 64 * 2);
    float* sl   = (float*)take((size_t)N * 4);
    float* sr   = (float*)take((size_t)N * 4);
    int* bucketed = (int*)y;   // consumed by sort_bucket before gemm writes y
    (void)ws_size;

    const int nbN = (N + 255) / 256;
    const int nbC = (E + CHUNK - 1) / CHUNK;
    const int nbW = (N + 3) / 4;
    const int nbG = (N + 63) / 64;

    // CSR build (shared by all 3 layers)
    zero_i<<<(NB + 255) / 256, 256, 0, stream>>>(bcnt, NB);
    hist_bucket<<<nbC, 256, 0, stream>>>(dstv, bcnt, E, NB);
    scan_bucket<<<1, 1024, 0, stream>>>(bcnt, boff, bcur, NB);
    scatter_bucket<<<nbC, 256, 0, stream>>>(srcv, dstv, bcur, bucketed, E, NB);
    sort_bucket<<<NB, 256, 0, stream>>>(bucketed, boff, deg, offs, csr, N);

    cat_wt<<<(128 * 128 + 255) / 256, 256, 0, stream>>>(wl0, wr0, w0t, 128, 7);
    cat_wt<<<(128 * 64 + 255) / 256, 256, 0, stream>>>(wl1, wr1, w1t, 64, 6);

    // layer 0
    gemm_mfma<128, false><<<nbG, 256, 0, stream>>>((const void*)x, w0t, y, N);
    agg_relu<<<nbW, 256, 0, stream>>>(y, csr, offs, deg, b0, h, N);
    // layer 1
    gemm_mfma<64, true><<<nbG, 256, 0, stream>>>((const void*)h, w1t, y, N);
    agg_relu<<<nbW, 256, 0, stream>>>(y, csr, offs, deg, b1, h, N);
    // layer 2 + sigmoid
    gemv2<<<nbW, 256, 0, stream>>>(h, wl2, wr2, sl, sr, N);
    final_k<<<nbN, 256, 0, stream>>>(sl, sr, csr, offs, deg, b2, out, N);
}

// Round 4
// 343.179 us; speedup vs baseline: 1.6327x; 1.0686x over previous
//
#include <hip/hip_runtime.h>
#include <hip/hip_bf16.h>
#include <math.h>

// ---------------------------------------------------------------------------
// GraphSAGE (3-layer, mean aggr), N=100000, E=1600000.
// mean_agg(x) @ W == mean_agg(x @ W): GEMMs first, aggregate narrow messages.
// R3->R4: agg_relu reworked — two 32-lane halves per wave, each half reads a
// full 128 B bf16 message row as one uint/lane (2 packed channels), so one
// load instruction covers 2 edges; halves combined via shfl_xor(32).
// Layer-1 agg fuses the final-layer GEMV (sl = h1.wl2, sr = h1.wr2) so h1 is
// never materialized. CSR build via two-level counting sort (R2, unchanged).
// ---------------------------------------------------------------------------

#define SHIFT 7
#define BKT 128
#define CHUNK 4096

typedef __bf16 bf16_t;
typedef bf16_t bf16x8 __attribute__((ext_vector_type(8)));
typedef float f32x4 __attribute__((ext_vector_type(4)));

__global__ __launch_bounds__(256) void zero_i(int* __restrict__ p, int n) {
    int i = blockIdx.x * 256 + threadIdx.x;
    if (i < n) p[i] = 0;
}

// ---- CSR build pass A1: histogram of dst>>SHIFT ----
__global__ __launch_bounds__(256) void hist_bucket(const int* __restrict__ dstv,
                                                   int* __restrict__ bucket_cnt,
                                                   int E, int NB) {
    __shared__ int h[1024];
    for (int i = threadIdx.x; i < NB; i += 256) h[i] = 0;
    __syncthreads();
    int base = blockIdx.x * CHUNK;
#pragma unroll
    for (int k = 0; k < CHUNK / 256; ++k) {
        int e = base + threadIdx.x + k * 256;
        if (e < E) atomicAdd(&h[dstv[e] >> SHIFT], 1);
    }
    __syncthreads();
    for (int i = threadIdx.x; i < NB; i += 256)
        if (h[i]) atomicAdd(&bucket_cnt[i], h[i]);
}

// ---- pass A2: exclusive scan of bucket counts ----
__global__ __launch_bounds__(1024) void scan_bucket(const int* __restrict__ cnt,
                                                    int* __restrict__ boff,
                                                    int* __restrict__ bcur, int NB) {
    __shared__ int s[1024];
    int t = threadIdx.x;
    int v = (t < NB) ? cnt[t] : 0;
    s[t] = v;
    __syncthreads();
    for (int d = 1; d < 1024; d <<= 1) {
        int x = (t >= d) ? s[t - d] : 0;
        __syncthreads();
        s[t] += x;
        __syncthreads();
    }
    if (t < NB) {
        int o = s[t] - v;
        boff[t] = o;
        bcur[t] = o;
    }
    if (t == NB - 1) boff[NB] = s[t];
}

// ---- pass A3: LDS-staged bucket scatter ----
__global__ __launch_bounds__(256) void scatter_bucket(const int* __restrict__ srcv,
                                                      const int* __restrict__ dstv,
                                                      int* __restrict__ bcur,
                                                      int* __restrict__ bucketed,
                                                      int E, int NB) {
    __shared__ int hist[1024];
    __shared__ int offl[1024];
    __shared__ int basel[1024];
    __shared__ int partial[256];
    __shared__ int posA[CHUNK];
    __shared__ int valA[CHUNK];
    const int t = threadIdx.x;
    for (int i = t; i < NB; i += 256) hist[i] = 0;
    __syncthreads();

    const int cbase = blockIdx.x * CHUNK;
    int bk[CHUNK / 256], rk[CHUNK / 256], vv[CHUNK / 256];
#pragma unroll
    for (int k = 0; k < CHUNK / 256; ++k) {
        int e = cbase + t + k * 256;
        if (e < E) {
            int d = dstv[e];
            int s = srcv[e];
            int b = d >> SHIFT;
            bk[k] = b;
            rk[k] = atomicAdd(&hist[b], 1);
            vv[k] = (s << SHIFT) | (d & (BKT - 1));
        } else {
            bk[k] = -1;
        }
    }
    __syncthreads();

    for (int b = t; b < NB; b += 256) {
        int c = hist[b];
        basel[b] = c ? atomicAdd(&bcur[b], c) : 0;
    }
    {
        int g = t * 4;
        int a0 = (g + 0 < NB) ? hist[g + 0] : 0;
        int a1 = (g + 1 < NB) ? hist[g + 1] : 0;
        int a2 = (g + 2 < NB) ? hist[g + 2] : 0;
        int a3 = (g + 3 < NB) ? hist[g + 3] : 0;
        int sum = a0 + a1 + a2 + a3;
        partial[t] = sum;
        __syncthreads();
        for (int d = 1; d < 256; d <<= 1) {
            int x = (t >= d) ? partial[t - d] : 0;
            __syncthreads();
            partial[t] += x;
            __syncthreads();
        }
        int ex = partial[t] - sum;
        if (g + 0 < NB) offl[g + 0] = ex;
        if (g + 1 < NB) offl[g + 1] = ex + a0;
        if (g + 2 < NB) offl[g + 2] = ex + a0 + a1;
        if (g + 3 < NB) offl[g + 3] = ex + a0 + a1 + a2;
    }
    __syncthreads();

    int nloc = E - cbase;
    if (nloc > CHUNK) nloc = CHUNK;
#pragma unroll
    for (int k = 0; k < CHUNK / 256; ++k) {
        if (bk[k] >= 0) {
            int slot = offl[bk[k]] + rk[k];
            posA[slot] = basel[bk[k]] + rk[k];
            valA[slot] = vv[k];
        }
    }
    __syncthreads();
    for (int j = t; j < nloc; j += 256) bucketed[posA[j]] = valA[j];
}

// ---- pass B: per-bucket counting sort -> deg, offs, csr ----
__global__ __launch_bounds__(256) void sort_bucket(const int* __restrict__ bucketed,
                                                   const int* __restrict__ boff,
                                                   int* __restrict__ deg,
                                                   int* __restrict__ offs,
                                                   int* __restrict__ csr, int N) {
    __shared__ int cnt[BKT];
    __shared__ int sc[BKT];
    __shared__ int cur[BKT];
    const int b = blockIdx.x;
    const int t = threadIdx.x;
    const int ebase = boff[b], eend = boff[b + 1];
    if (t < BKT) cnt[t] = 0;
    __syncthreads();
    for (int i = ebase + t; i < eend; i += 256)
        atomicAdd(&cnt[bucketed[i] & (BKT - 1)], 1);
    __syncthreads();
    int v = (t < BKT) ? cnt[t] : 0;
    if (t < BKT) sc[t] = v;
    __syncthreads();
    for (int d = 1; d < BKT; d <<= 1) {
        int x = (t < BKT && t >= d) ? sc[t - d] : 0;
        __syncthreads();
        if (t < BKT) sc[t] += x;
        __syncthreads();
    }
    if (t < BKT) {
        int ex = sc[t] - v;
        cur[t] = ex;
        int dst = (b << SHIFT) + t;
        if (dst < N) {
            deg[dst] = v;
            offs[dst] = ebase + ex;
        }
    }
    __syncthreads();
    for (int i = ebase + t; i < eend; i += 256) {
        int w = bucketed[i];
        int p = atomicAdd(&cur[w & (BKT - 1)], 1);
        csr[ebase + p] = w >> SHIFT;
    }
}

// both weight concats (bf16, transposed) in one launch
__global__ __launch_bounds__(256) void prep_w(const float* __restrict__ wl0,
                                              const float* __restrict__ wr0,
                                              const float* __restrict__ wl1,
                                              const float* __restrict__ wr1,
                                              bf16_t* __restrict__ w0t,
                                              bf16_t* __restrict__ w1t) {
    int idx = blockIdx.x * 256 + threadIdx.x;
    if (idx < 128 * 128) {
        int j = idx >> 7, k = idx & 127;
        float v = (j < 64) ? wl0[k * 64 + j] : wr0[k * 64 + (j - 64)];
        w0t[idx] = (bf16_t)v;
    } else if (idx < 128 * 128 + 128 * 64) {
        int i2 = idx - 128 * 128;
        int j = i2 >> 6, k = i2 & 63;
        float v = (j < 64) ? wl1[k * 64 + j] : wr1[k * 64 + (j - 64)];
        w1t[i2] = (bf16_t)v;
    }
}

// Y[N x 128] (bf16) = A[N x KTOT] @ W[KTOT x 128], via 16x16x32 bf16 MFMA.
template <int KTOT, bool AIN_BF16>
__global__ __launch_bounds__(256) void gemm_mfma(const void* __restrict__ Ain,
                                                 const bf16_t* __restrict__ Wt,
                                                 bf16_t* __restrict__ Y, int N) {
    const int lane = threadIdx.x & 63;
    const int wv = threadIdx.x >> 6;
    const int r0 = blockIdx.x * 64 + wv * 16;
    const int rr = lane & 15;
    const int quad = lane >> 4;
    const int row_store = r0 + rr;
    int row = (row_store < N) ? row_store : (N - 1);
    constexpr int NK = KTOT / 32;

    bf16x8 xf[NK];
    if (AIN_BF16) {
        const bf16_t* A = (const bf16_t*)Ain;
#pragma unroll
        for (int kk = 0; kk < NK; ++kk)
            xf[kk] = *(const bf16x8*)&A[(size_t)row * KTOT + kk * 32 + quad * 8];
    } else {
        const float* A = (const float*)Ain;
#pragma unroll
        for (int kk = 0; kk < NK; ++kk) {
            const float* ap = &A[(size_t)row * KTOT + kk * 32 + quad * 8];
            float4 f0 = *(const float4*)ap;
            float4 f1 = *(const float4*)(ap + 4);
            union { bf16x8 v; bf16_t h[8]; } u;
            u.h[0] = (bf16_t)f0.x; u.h[1] = (bf16_t)f0.y;
            u.h[2] = (bf16_t)f0.z; u.h[3] = (bf16_t)f0.w;
            u.h[4] = (bf16_t)f1.x; u.h[5] = (bf16_t)f1.y;
            u.h[6] = (bf16_t)f1.z; u.h[7] = (bf16_t)f1.w;
            xf[kk] = u.v;
        }
    }

#pragma unroll
    for (int c = 0; c < 8; ++c) {
        f32x4 acc = {0.f, 0.f, 0.f, 0.f};
#pragma unroll
        for (int kk = 0; kk < NK; ++kk) {
            bf16x8 wf = *(const bf16x8*)&Wt[(size_t)(c * 16 + rr) * KTOT + kk * 32 + quad * 8];
            acc = __builtin_amdgcn_mfma_f32_16x16x32_bf16(wf, xf[kk], acc, 0, 0, 0);
        }
        if (row_store < N) {
            union { bf16_t h[4]; uint2 u; } p;
            p.h[0] = (bf16_t)acc[0]; p.h[1] = (bf16_t)acc[1];
            p.h[2] = (bf16_t)acc[2]; p.h[3] = (bf16_t)acc[3];
            *(uint2*)&Y[(size_t)row_store * 128 + c * 16 + quad * 4] = p.u;
        }
    }
}

// agg_relu: one wave per node, two 32-lane halves; each half reads a full
// 128 B message row as uint/lane (2 packed bf16 channels) -> one load instr
// covers 2 edges. FUSED variant computes sl = h.wl2, sr = h.wr2 instead of
// storing h (final-layer GEMV fused in).
template <bool FUSED>
__global__ __launch_bounds__(256) void agg_relu(const bf16_t* __restrict__ y,
                                                const int* __restrict__ csr,
                                                const int* __restrict__ offs,
                                                const int* __restrict__ deg,
                                                const float* __restrict__ bias,
                                                bf16_t* __restrict__ h,
                                                const float* __restrict__ wl2,
                                                const float* __restrict__ wr2,
                                                float* __restrict__ sl,
                                                float* __restrict__ sr, int N) {
    int wid = blockIdx.x * 4 + (threadIdx.x >> 6);
    if (wid >= N) return;
    const int lane = threadIdx.x & 63;
    const int half = lane >> 5;
    const int ch = (lane & 31) * 2;
    const int base = offs[wid];
    const int d = deg[wid];

    float ax = 0.f, ay = 0.f;
    const int npairs = d >> 1;
    int p = 0;
    for (; p + 2 <= npairs; p += 2) {
        int e0 = base + 2 * p + half;
        int s0 = csr[e0];
        int s1 = csr[e0 + 2];
        uint v0 = *(const uint*)&y[(size_t)s0 * 128 + ch];
        uint v1 = *(const uint*)&y[(size_t)s1 * 128 + ch];
        ax += __uint_as_float(v0 << 16);
        ay += __uint_as_float(v0 & 0xffff0000u);
        ax += __uint_as_float(v1 << 16);
        ay += __uint_as_float(v1 & 0xffff0000u);
    }
    if (p < npairs) {
        int s0 = csr[base + 2 * p + half];
        uint v0 = *(const uint*)&y[(size_t)s0 * 128 + ch];
        ax += __uint_as_float(v0 << 16);
        ay += __uint_as_float(v0 & 0xffff0000u);
    }
    if ((d & 1) && half == 0) {
        int s0 = csr[base + d - 1];
        uint v0 = *(const uint*)&y[(size_t)s0 * 128 + ch];
        ax += __uint_as_float(v0 << 16);
        ay += __uint_as_float(v0 & 0xffff0000u);
    }
    ax += __shfl_xor(ax, 32);
    ay += __shfl_xor(ay, 32);

    float inv = 1.f / ((d > 0) ? (float)d : 1.f);
    uint vs = *(const uint*)&y[(size_t)wid * 128 + 64 + ch];
    float2 bv = *(const float2*)&bias[ch];
    float vx = fmaxf(ax * inv + __uint_as_float(vs << 16) + bv.x, 0.f);
    float vy = fmaxf(ay * inv + __uint_as_float(vs & 0xffff0000u) + bv.y, 0.f);

    if (!FUSED) {
        if (half == 0) {
            union { bf16_t b[2]; uint u; } pk;
            pk.b[0] = (bf16_t)vx;
            pk.b[1] = (bf16_t)vy;
            *(uint*)&h[(size_t)wid * 64 + ch] = pk.u;
        }
    } else {
        // each half independently covers all 64 channels -> butterfly width 32
        float a = vx * wl2[ch] + vy * wl2[ch + 1];
        float b = vx * wr2[ch] + vy * wr2[ch + 1];
#pragma unroll
        for (int off = 16; off; off >>= 1) {
            a += __shfl_xor(a, off);
            b += __shfl_xor(b, off);
        }
        if (lane == 0) {
            sl[wid] = a;
            sr[wid] = b;
        }
    }
}

__global__ __launch_bounds__(256) void final_k(const float* __restrict__ sl,
                                               const float* __restrict__ sr,
                                               const int* __restrict__ csr,
                                               const int* __restrict__ offs,
                                               const int* __restrict__ deg,
                                               const float* __restrict__ b2,
                                               float* __restrict__ out, int N) {
    int i = blockIdx.x * 256 + threadIdx.x;
    if (i >= N) return;
    int base = offs[i];
    int d = deg[i];
    float acc = 0.f;
    for (int e = 0; e < d; ++e) acc += sl[csr[base + e]];
    float m = (d > 0) ? (float)d : 1.f;
    float v = acc / m + sr[i] + b2[0];
    out[i] = 1.f / (1.f + expf(-v));
}

extern "C" void kernel_launch(void* const* d_in, const int* in_sizes, int n_in,
                              void* d_out, int out_size, void* d_ws, size_t ws_size,
                              hipStream_t stream) {
    const float* x  = (const float*)d_in[0];
    const int*  ei  = (const int*)d_in[1];
    const float* wl0 = (const float*)d_in[2];
    const float* wr0 = (const float*)d_in[3];
    const float* b0  = (const float*)d_in[4];
    const float* wl1 = (const float*)d_in[5];
    const float* wr1 = (const float*)d_in[6];
    const float* b1  = (const float*)d_in[7];
    const float* wl2 = (const float*)d_in[8];
    const float* wr2 = (const float*)d_in[9];
    const float* b2  = (const float*)d_in[10];
    float* out = (float*)d_out;

    const int E = in_sizes[1] / 2;
    const int N = out_size;
    const int* srcv = ei;
    const int* dstv = ei + E;
    const int NB = (N + BKT - 1) >> SHIFT;   // 782

    char* ws = (char*)d_ws;
    size_t o = 0;
    auto take = [&](size_t nbytes) -> void* {
        void* p = ws + o;
        o = (o + nbytes + 255) & ~(size_t)255;
        return p;
    };
    int* deg    = (int*)take((size_t)N * 4);
    int* offs   = (int*)take((size_t)N * 4);
    int* bcnt   = (int*)take((size_t)(NB + 2) * 4);
    int* boff   = (int*)take((size_t)(NB + 2) * 4);
    int* bcur   = (int*)take((size_t)(NB + 2) * 4);
    int* csr    = (int*)take((size_t)E * 4);
    bf16_t* w0t = (bf16_t*)take(128 * 128 * 2);
    bf16_t* w1t = (bf16_t*)take(128 * 64 * 2);
    bf16_t* y   = (bf16_t*)take((size_t)N * 128 * 2);
    bf16_t* h   = (bf16_t*)take((size_t)N * 64 * 2);
    float* sl   = (float*)take((size_t)N * 4);
    float* sr   = (float*)take((size_t)N * 4);
    int* bucketed = (int*)y;   // consumed by sort_bucket before gemm writes y
    (void)ws_size;

    const int nbN = (N + 255) / 256;
    const int nbC = (E + CHUNK - 1) / CHUNK;
    const int nbW = (N + 3) / 4;
    const int nbG = (N + 63) / 64;

    // CSR build (shared by all 3 layers)
    zero_i<<<(NB + 255) / 256, 256, 0, stream>>>(bcnt, NB);
    hist_bucket<<<nbC, 256, 0, stream>>>(dstv, bcnt, E, NB);
    scan_bucket<<<1, 1024, 0, stream>>>(bcnt, boff, bcur, NB);
    scatter_bucket<<<nbC, 256, 0, stream>>>(srcv, dstv, bcur, bucketed, E, NB);
    sort_bucket<<<NB, 256, 0, stream>>>(bucketed, boff, deg, offs, csr, N);

    prep_w<<<(128 * 128 + 128 * 64 + 255) / 256, 256, 0, stream>>>(wl0, wr0, wl1, wr1, w0t, w1t);

    // layer 0
    gemm_mfma<128, false><<<nbG, 256, 0, stream>>>((const void*)x, w0t, y, N);
    agg_relu<false><<<nbW, 256, 0, stream>>>(y, csr, offs, deg, b0, h,
                                             nullptr, nullptr, nullptr, nullptr, N);
    // layer 1 (fused with final-layer GEMV)
    gemm_mfma<64, true><<<nbG, 256, 0, stream>>>((const void*)h, w1t, y, N);
    agg_relu<true><<<nbW, 256, 0, stream>>>(y, csr, offs, deg, b1, nullptr,
                                            wl2, wr2, sl, sr, N);
    // final aggregation + sigmoid
    final_k<<<nbN, 256, 0, stream>>>(sl, sr, csr, offs, deg, b2, out, N);
}

// Round 6
// 330.417 us; speedup vs baseline: 1.6958x; 1.0386x over previous
//
#include <hip/hip_runtime.h>
#include <hip/hip_bf16.h>
#include <math.h>

// ---------------------------------------------------------------------------
// GraphSAGE (3-layer, mean aggr), N=100000, E=1600000.
// mean_agg(x) @ W == mean_agg(x @ W): GEMMs first, aggregate narrow messages.
// R5->R6 FIX: R5's odd-edge path called __shfl inside a divergent branch
// (half==0); ds_bpermute from an exec-masked lane is UNDEFINED -> garbage
// src index for odd-degree>=33 nodes (absmax 0.0195, fail). The last-edge
// shuffle now executes under FULL exec before the branch.
// agg_relu: one coalesced csr load/node + __shfl for indices (no csr->y
// memory dependency), 4-pair unroll -> 8 gathers in flight per wave.
// CSR build via two-level counting sort (R2, unchanged).
// ---------------------------------------------------------------------------

#define SHIFT 7
#define BKT 128
#define CHUNK 4096

typedef __bf16 bf16_t;
typedef bf16_t bf16x8 __attribute__((ext_vector_type(8)));
typedef float f32x4 __attribute__((ext_vector_type(4)));

__global__ __launch_bounds__(256) void zero_i(int* __restrict__ p, int n) {
    int i = blockIdx.x * 256 + threadIdx.x;
    if (i < n) p[i] = 0;
}

// ---- CSR build pass A1: histogram of dst>>SHIFT ----
__global__ __launch_bounds__(256) void hist_bucket(const int* __restrict__ dstv,
                                                   int* __restrict__ bucket_cnt,
                                                   int E, int NB) {
    __shared__ int h[1024];
    for (int i = threadIdx.x; i < NB; i += 256) h[i] = 0;
    __syncthreads();
    int base = blockIdx.x * CHUNK;
#pragma unroll
    for (int k = 0; k < CHUNK / 256; ++k) {
        int e = base + threadIdx.x + k * 256;
        if (e < E) atomicAdd(&h[dstv[e] >> SHIFT], 1);
    }
    __syncthreads();
    for (int i = threadIdx.x; i < NB; i += 256)
        if (h[i]) atomicAdd(&bucket_cnt[i], h[i]);
}

// ---- pass A2: exclusive scan of bucket counts ----
__global__ __launch_bounds__(1024) void scan_bucket(const int* __restrict__ cnt,
                                                    int* __restrict__ boff,
                                                    int* __restrict__ bcur, int NB) {
    __shared__ int s[1024];
    int t = threadIdx.x;
    int v = (t < NB) ? cnt[t] : 0;
    s[t] = v;
    __syncthreads();
    for (int d = 1; d < 1024; d <<= 1) {
        int x = (t >= d) ? s[t - d] : 0;
        __syncthreads();
        s[t] += x;
        __syncthreads();
    }
    if (t < NB) {
        int o = s[t] - v;
        boff[t] = o;
        bcur[t] = o;
    }
    if (t == NB - 1) boff[NB] = s[t];
}

// ---- pass A3: LDS-staged bucket scatter ----
__global__ __launch_bounds__(256) void scatter_bucket(const int* __restrict__ srcv,
                                                      const int* __restrict__ dstv,
                                                      int* __restrict__ bcur,
                                                      int* __restrict__ bucketed,
                                                      int E, int NB) {
    __shared__ int hist[1024];
    __shared__ int offl[1024];
    __shared__ int basel[1024];
    __shared__ int partial[256];
    __shared__ int posA[CHUNK];
    __shared__ int valA[CHUNK];
    const int t = threadIdx.x;
    for (int i = t; i < NB; i += 256) hist[i] = 0;
    __syncthreads();

    const int cbase = blockIdx.x * CHUNK;
    int bk[CHUNK / 256], rk[CHUNK / 256], vv[CHUNK / 256];
#pragma unroll
    for (int k = 0; k < CHUNK / 256; ++k) {
        int e = cbase + t + k * 256;
        if (e < E) {
            int d = dstv[e];
            int s = srcv[e];
            int b = d >> SHIFT;
            bk[k] = b;
            rk[k] = atomicAdd(&hist[b], 1);
            vv[k] = (s << SHIFT) | (d & (BKT - 1));
        } else {
            bk[k] = -1;
        }
    }
    __syncthreads();

    for (int b = t; b < NB; b += 256) {
        int c = hist[b];
        basel[b] = c ? atomicAdd(&bcur[b], c) : 0;
    }
    {
        int g = t * 4;
        int a0 = (g + 0 < NB) ? hist[g + 0] : 0;
        int a1 = (g + 1 < NB) ? hist[g + 1] : 0;
        int a2 = (g + 2 < NB) ? hist[g + 2] : 0;
        int a3 = (g + 3 < NB) ? hist[g + 3] : 0;
        int sum = a0 + a1 + a2 + a3;
        partial[t] = sum;
        __syncthreads();
        for (int d = 1; d < 256; d <<= 1) {
            int x = (t >= d) ? partial[t - d] : 0;
            __syncthreads();
            partial[t] += x;
            __syncthreads();
        }
        int ex = partial[t] - sum;
        if (g + 0 < NB) offl[g + 0] = ex;
        if (g + 1 < NB) offl[g + 1] = ex + a0;
        if (g + 2 < NB) offl[g + 2] = ex + a0 + a1;
        if (g + 3 < NB) offl[g + 3] = ex + a0 + a1 + a2;
    }
    __syncthreads();

    int nloc = E - cbase;
    if (nloc > CHUNK) nloc = CHUNK;
#pragma unroll
    for (int k = 0; k < CHUNK / 256; ++k) {
        if (bk[k] >= 0) {
            int slot = offl[bk[k]] + rk[k];
            posA[slot] = basel[bk[k]] + rk[k];
            valA[slot] = vv[k];
        }
    }
    __syncthreads();
    for (int j = t; j < nloc; j += 256) bucketed[posA[j]] = valA[j];
}

// ---- pass B: per-bucket counting sort -> deg, offs, csr ----
__global__ __launch_bounds__(256) void sort_bucket(const int* __restrict__ bucketed,
                                                   const int* __restrict__ boff,
                                                   int* __restrict__ deg,
                                                   int* __restrict__ offs,
                                                   int* __restrict__ csr, int N) {
    __shared__ int cnt[BKT];
    __shared__ int sc[BKT];
    __shared__ int cur[BKT];
    const int b = blockIdx.x;
    const int t = threadIdx.x;
    const int ebase = boff[b], eend = boff[b + 1];
    if (t < BKT) cnt[t] = 0;
    __syncthreads();
    for (int i = ebase + t; i < eend; i += 256)
        atomicAdd(&cnt[bucketed[i] & (BKT - 1)], 1);
    __syncthreads();
    int v = (t < BKT) ? cnt[t] : 0;
    if (t < BKT) sc[t] = v;
    __syncthreads();
    for (int d = 1; d < BKT; d <<= 1) {
        int x = (t < BKT && t >= d) ? sc[t - d] : 0;
        __syncthreads();
        if (t < BKT) sc[t] += x;
        __syncthreads();
    }
    if (t < BKT) {
        int ex = sc[t] - v;
        cur[t] = ex;
        int dst = (b << SHIFT) + t;
        if (dst < N) {
            deg[dst] = v;
            offs[dst] = ebase + ex;
        }
    }
    __syncthreads();
    for (int i = ebase + t; i < eend; i += 256) {
        int w = bucketed[i];
        int p = atomicAdd(&cur[w & (BKT - 1)], 1);
        csr[ebase + p] = w >> SHIFT;
    }
}

// both weight concats (bf16, transposed) in one launch
__global__ __launch_bounds__(256) void prep_w(const float* __restrict__ wl0,
                                              const float* __restrict__ wr0,
                                              const float* __restrict__ wl1,
                                              const float* __restrict__ wr1,
                                              bf16_t* __restrict__ w0t,
                                              bf16_t* __restrict__ w1t) {
    int idx = blockIdx.x * 256 + threadIdx.x;
    if (idx < 128 * 128) {
        int j = idx >> 7, k = idx & 127;
        float v = (j < 64) ? wl0[k * 64 + j] : wr0[k * 64 + (j - 64)];
        w0t[idx] = (bf16_t)v;
    } else if (idx < 128 * 128 + 128 * 64) {
        int i2 = idx - 128 * 128;
        int j = i2 >> 6, k = i2 & 63;
        float v = (j < 64) ? wl1[k * 64 + j] : wr1[k * 64 + (j - 64)];
        w1t[i2] = (bf16_t)v;
    }
}

// Y[N x 128] (bf16) = A[N x KTOT] @ W[KTOT x 128], via 16x16x32 bf16 MFMA.
template <int KTOT, bool AIN_BF16>
__global__ __launch_bounds__(256) void gemm_mfma(const void* __restrict__ Ain,
                                                 const bf16_t* __restrict__ Wt,
                                                 bf16_t* __restrict__ Y, int N) {
    const int lane = threadIdx.x & 63;
    const int wv = threadIdx.x >> 6;
    const int r0 = blockIdx.x * 64 + wv * 16;
    const int rr = lane & 15;
    const int quad = lane >> 4;
    const int row_store = r0 + rr;
    int row = (row_store < N) ? row_store : (N - 1);
    constexpr int NK = KTOT / 32;

    bf16x8 xf[NK];
    if (AIN_BF16) {
        const bf16_t* A = (const bf16_t*)Ain;
#pragma unroll
        for (int kk = 0; kk < NK; ++kk)
            xf[kk] = *(const bf16x8*)&A[(size_t)row * KTOT + kk * 32 + quad * 8];
    } else {
        const float* A = (const float*)Ain;
#pragma unroll
        for (int kk = 0; kk < NK; ++kk) {
            const float* ap = &A[(size_t)row * KTOT + kk * 32 + quad * 8];
            float4 f0 = *(const float4*)ap;
            float4 f1 = *(const float4*)(ap + 4);
            union { bf16x8 v; bf16_t h[8]; } u;
            u.h[0] = (bf16_t)f0.x; u.h[1] = (bf16_t)f0.y;
            u.h[2] = (bf16_t)f0.z; u.h[3] = (bf16_t)f0.w;
            u.h[4] = (bf16_t)f1.x; u.h[5] = (bf16_t)f1.y;
            u.h[6] = (bf16_t)f1.z; u.h[7] = (bf16_t)f1.w;
            xf[kk] = u.v;
        }
    }

#pragma unroll
    for (int c = 0; c < 8; ++c) {
        f32x4 acc = {0.f, 0.f, 0.f, 0.f};
#pragma unroll
        for (int kk = 0; kk < NK; ++kk) {
            bf16x8 wf = *(const bf16x8*)&Wt[(size_t)(c * 16 + rr) * KTOT + kk * 32 + quad * 8];
            acc = __builtin_amdgcn_mfma_f32_16x16x32_bf16(wf, xf[kk], acc, 0, 0, 0);
        }
        if (row_store < N) {
            union { bf16_t h[4]; uint2 u; } p;
            p.h[0] = (bf16_t)acc[0]; p.h[1] = (bf16_t)acc[1];
            p.h[2] = (bf16_t)acc[2]; p.h[3] = (bf16_t)acc[3];
            *(uint2*)&Y[(size_t)row_store * 128 + c * 16 + quad * 4] = p.u;
        }
    }
}

// agg_relu: one wave per node, two 32-lane halves (half h takes edges
// e==h mod 2); each half reads a 128 B bf16 message row as uint/lane.
// Edge src indices come from ONE coalesced csr load + __shfl under FULL
// exec; 4-pair unroll -> 8 independent y-gathers in flight per wave.
template <bool FUSED>
__global__ __launch_bounds__(256) void agg_relu(const bf16_t* __restrict__ y,
                                                const int* __restrict__ csr,
                                                const int* __restrict__ offs,
                                                const int* __restrict__ deg,
                                                const float* __restrict__ bias,
                                                bf16_t* __restrict__ h,
                                                const float* __restrict__ wl2,
                                                const float* __restrict__ wr2,
                                                float* __restrict__ sl,
                                                float* __restrict__ sr, int N) {
    int wid = blockIdx.x * 4 + (threadIdx.x >> 6);
    if (wid >= N) return;                    // wave-uniform
    const int lane = threadIdx.x & 63;
    const int half = lane >> 5;
    const int ch = (lane & 31) * 2;
    const int base = offs[wid];
    const int d = deg[wid];

    // one coalesced load: lane l holds src of edge l (l < min(d,64))
    int sidx = (lane < d) ? csr[base + lane] : 0;

    // last-edge index, resolved under FULL exec (divergent __shfl from a
    // masked lane is undefined — this was R5's correctness bug)
    int lastLane = (d > 0 && d - 1 < 64) ? (d - 1) : 0;
    int s_last = __shfl(sidx, lastLane);

    float ax = 0.f, ay = 0.f;
    const int npairs = d >> 1;
    const int pm = (npairs < 28) ? npairs : 28;   // shfl-safe region
    int p = 0;
    for (; p + 4 <= pm; p += 4) {
        int s0 = __shfl(sidx, 2 * p + half);
        int s1 = __shfl(sidx, 2 * p + 2 + half);
        int s2 = __shfl(sidx, 2 * p + 4 + half);
        int s3 = __shfl(sidx, 2 * p + 6 + half);
        uint v0 = *(const uint*)&y[(size_t)s0 * 128 + ch];
        uint v1 = *(const uint*)&y[(size_t)s1 * 128 + ch];
        uint v2 = *(const uint*)&y[(size_t)s2 * 128 + ch];
        uint v3 = *(const uint*)&y[(size_t)s3 * 128 + ch];
        ax += __uint_as_float(v0 << 16) + __uint_as_float(v1 << 16) +
              __uint_as_float(v2 << 16) + __uint_as_float(v3 << 16);
        ay += __uint_as_float(v0 & 0xffff0000u) + __uint_as_float(v1 & 0xffff0000u) +
              __uint_as_float(v2 & 0xffff0000u) + __uint_as_float(v3 & 0xffff0000u);
    }
    for (; p < npairs; ++p) {          // tail pairs: direct csr loads
        int s0 = csr[base + 2 * p + half];
        uint v0 = *(const uint*)&y[(size_t)s0 * 128 + ch];
        ax += __uint_as_float(v0 << 16);
        ay += __uint_as_float(v0 & 0xffff0000u);
    }
    if ((d & 1) && half == 0) {        // odd last edge, half 0 only
        int s0 = (d - 1 < 64) ? s_last : csr[base + d - 1];
        uint v0 = *(const uint*)&y[(size_t)s0 * 128 + ch];
        ax += __uint_as_float(v0 << 16);
        ay += __uint_as_float(v0 & 0xffff0000u);
    }
    ax += __shfl_xor(ax, 32);
    ay += __shfl_xor(ay, 32);

    float inv = 1.f / ((d > 0) ? (float)d : 1.f);
    uint vs = *(const uint*)&y[(size_t)wid * 128 + 64 + ch];
    float2 bv = *(const float2*)&bias[ch];
    float vx = fmaxf(ax * inv + __uint_as_float(vs << 16) + bv.x, 0.f);
    float vy = fmaxf(ay * inv + __uint_as_float(vs & 0xffff0000u) + bv.y, 0.f);

    if (!FUSED) {
        if (half == 0) {
            union { bf16_t b[2]; uint u; } pk;
            pk.b[0] = (bf16_t)vx;
            pk.b[1] = (bf16_t)vy;
            *(uint*)&h[(size_t)wid * 64 + ch] = pk.u;
        }
    } else {
        float a = vx * wl2[ch] + vy * wl2[ch + 1];
        float b = vx * wr2[ch] + vy * wr2[ch + 1];
#pragma unroll
        for (int off = 16; off; off >>= 1) {
            a += __shfl_xor(a, off);
            b += __shfl_xor(b, off);
        }
        if (lane == 0) {
            sl[wid] = a;
            sr[wid] = b;
        }
    }
}

// final: wave per node, lane-parallel sl gather + butterfly reduce + sigmoid
__global__ __launch_bounds__(256) void final_k(const float* __restrict__ sl,
                                               const float* __restrict__ sr,
                                               const int* __restrict__ csr,
                                               const int* __restrict__ offs,
                                               const int* __restrict__ deg,
                                               const float* __restrict__ b2,
                                               float* __restrict__ out, int N) {
    int wid = blockIdx.x * 4 + (threadIdx.x >> 6);
    if (wid >= N) return;
    const int lane = threadIdx.x & 63;
    const int base = offs[wid];
    const int d = deg[wid];
    float acc = 0.f;
    for (int e = lane; e < d; e += 64) acc += sl[csr[base + e]];
#pragma unroll
    for (int off = 32; off; off >>= 1) acc += __shfl_xor(acc, off);
    if (lane == 0) {
        float m = (d > 0) ? (float)d : 1.f;
        float v = acc / m + sr[wid] + b2[0];
        out[wid] = 1.f / (1.f + expf(-v));
    }
}

extern "C" void kernel_launch(void* const* d_in, const int* in_sizes, int n_in,
                              void* d_out, int out_size, void* d_ws, size_t ws_size,
                              hipStream_t stream) {
    const float* x  = (const float*)d_in[0];
    const int*  ei  = (const int*)d_in[1];
    const float* wl0 = (const float*)d_in[2];
    const float* wr0 = (const float*)d_in[3];
    const float* b0  = (const float*)d_in[4];
    const float* wl1 = (const float*)d_in[5];
    const float* wr1 = (const float*)d_in[6];
    const float* b1  = (const float*)d_in[7];
    const float* wl2 = (const float*)d_in[8];
    const float* wr2 = (const float*)d_in[9];
    const float* b2  = (const float*)d_in[10];
    float* out = (float*)d_out;

    const int E = in_sizes[1] / 2;
    const int N = out_size;
    const int* srcv = ei;
    const int* dstv = ei + E;
    const int NB = (N + BKT - 1) >> SHIFT;   // 782

    char* ws = (char*)d_ws;
    size_t o = 0;
    auto take = [&](size_t nbytes) -> void* {
        void* p = ws + o;
        o = (o + nbytes + 255) & ~(size_t)255;
        return p;
    };
    int* deg    = (int*)take((size_t)N * 4);
    int* offs   = (int*)take((size_t)N * 4);
    int* bcnt   = (int*)take((size_t)(NB + 2) * 4);
    int* boff   = (int*)take((size_t)(NB + 2) * 4);
    int* bcur   = (int*)take((size_t)(NB + 2) * 4);
    int* csr    = (int*)take((size_t)E * 4);
    bf16_t* w0t = (bf16_t*)take(128 * 128 * 2);
    bf16_t* w1t = (bf16_t*)take(128 * 64 * 2);
    bf16_t* y   = (bf16_t*)take((size_t)N * 128 * 2);
    bf16_t* h   = (bf16_t*)take((size_t)N * 64 * 2);
    float* sl   = (float*)take((size_t)N * 4);
    float* sr   = (float*)take((size_t)N * 4);
    int* bucketed = (int*)y;   // consumed by sort_bucket before gemm writes y
    (void)ws_size;

    const int nbC = (E + CHUNK - 1) / CHUNK;
    const int nbW = (N + 3) / 4;
    const int nbG = (N + 63) / 64;

    // CSR build (shared by all 3 layers)
    zero_i<<<(NB + 255) / 256, 256, 0, stream>>>(bcnt, NB);
    hist_bucket<<<nbC, 256, 0, stream>>>(dstv, bcnt, E, NB);
    scan_bucket<<<1, 1024, 0, stream>>>(bcnt, boff, bcur, NB);
    scatter_bucket<<<nbC, 256, 0, stream>>>(srcv, dstv, bcur, bucketed, E, NB);
    sort_bucket<<<NB, 256, 0, stream>>>(bucketed, boff, deg, offs, csr, N);

    prep_w<<<(128 * 128 + 128 * 64 + 255) / 256, 256, 0, stream>>>(wl0, wr0, wl1, wr1, w0t, w1t);

    // layer 0
    gemm_mfma<128, false><<<nbG, 256, 0, stream>>>((const void*)x, w0t, y, N);
    agg_relu<false><<<nbW, 256, 0, stream>>>(y, csr, offs, deg, b0, h,
                                             nullptr, nullptr, nullptr, nullptr, N);
    // layer 1 (fused with final-layer GEMV)
    gemm_mfma<64, true><<<nbG, 256, 0, stream>>>((const void*)h, w1t, y, N);
    agg_relu<true><<<nbW, 256, 0, stream>>>(y, csr, offs, deg, b1, nullptr,
                                            wl2, wr2, sl, sr, N);
    // final aggregation + sigmoid
    final_k<<<nbW, 256, 0, stream>>>(sl, sr, csr, offs, deg, b2, out, N);
}